// Round 6
// baseline (88.237 us; speedup 1.0000x reference)
//
#include <hip/hip_runtime.h>
#include <math.h>

// LSH attention: B=2, H=8, S=2048, D=64, 6 bits -> 64 buckets, exact-match.
// Phase 1: bucket codes for Q and K (fused, sign of X.rot)   [unchanged]
// Phase 2: stable counting sort; Q list 8-PADDED per bucket (sentinel -1)
// Phase 3: wave per 8 same-bucket queries, barrier-free. lane=key scores
//          (shared K-row gather, scalar Q reads), NO max-subtraction softmax
//          (exp direct, lane-distributed l, single end reduce), lane=dim PV.

constexpr int S_LEN = 2048;
constexpr int D = 64;
constexpr int NHASH = 6;
constexpr int BH = 16;     // B*H
constexpr int NB = 64;     // 2^NHASH
constexpr int QPAD = 8;    // queries per wave
constexpr int PADQ = S_LEN + (QPAD - 1) * NB;   // 2496: worst-case padded length

// ---- Phase 1: bucket codes for Q and K in one dispatch. One wave per vector.
__global__ __launch_bounds__(256) void lsh_buckets2(const float* __restrict__ Q,
                                                    const float* __restrict__ K,
                                                    const float* __restrict__ rot,
                                                    int* __restrict__ qb,
                                                    int* __restrict__ kb) {
    const int gw   = (blockIdx.x * 256 + threadIdx.x) >> 6;
    const int lane = threadIdx.x & 63;
    const bool isK = gw >= BH * S_LEN;
    const int wid  = isK ? gw - BH * S_LEN : gw;
    const float* X = isK ? K : Q;
    int* dst       = isK ? kb : qb;
    const int h    = (wid >> 11) & 7;

    const float x  = X[(size_t)wid * D + lane];
    const float* r = rot + (size_t)h * NHASH * D + lane;
    float p0 = x * r[0 * D], p1 = x * r[1 * D], p2 = x * r[2 * D];
    float p3 = x * r[3 * D], p4 = x * r[4 * D], p5 = x * r[5 * D];
#pragma unroll
    for (int off = 32; off >= 1; off >>= 1) {
        p0 += __shfl_xor(p0, off, 64);
        p1 += __shfl_xor(p1, off, 64);
        p2 += __shfl_xor(p2, off, 64);
        p3 += __shfl_xor(p3, off, 64);
        p4 += __shfl_xor(p4, off, 64);
        p5 += __shfl_xor(p5, off, 64);
    }
    int bucket = (p0 > 0.f ? 1 : 0) | (p1 > 0.f ? 2 : 0) | (p2 > 0.f ? 4 : 0) |
                 (p3 > 0.f ? 8 : 0) | (p4 > 0.f ? 16 : 0) | (p5 > 0.f ? 32 : 0);
    if (lane == 0) dst[wid] = bucket;
}

// ---- Phase 2: stable counting sort, one block per (which, bh). which: 0=Q 1=K
// Q side writes an 8-padded list (PADQ slots, -1 sentinels); K side unpadded +
// bucket_start table.
__global__ __launch_bounds__(256) void lsh_build_lists3(const int* __restrict__ qbuckets,
                                                        const int* __restrict__ kbuckets,
                                                        int* __restrict__ q_plist,
                                                        int* __restrict__ k_start,
                                                        int* __restrict__ k_list) {
    __shared__ unsigned short hist[256][NB + 1];
    __shared__ int base[NB + 1];
    const int which = blockIdx.x >> 4;   // 0 = Q (padded), 1 = K
    const int bh    = blockIdx.x & 15;
    const int tid   = threadIdx.x;
    const int* src  = (which ? kbuckets : qbuckets) + bh * S_LEN;
    int* blist      = which ? (k_list + bh * S_LEN) : (q_plist + bh * PADQ);

    if (!which) {  // prefill padded list with sentinels
        for (int t = tid; t < PADQ; t += 256) blist[t] = -1;
    }

    for (int b = 0; b <= NB; ++b) hist[tid][b] = 0;

    int myb[8];
#pragma unroll
    for (int i = 0; i < 8; ++i) {
        int b = src[tid * 8 + i];
        myb[i] = b;
        hist[tid][b]++;
    }
    __syncthreads();

    // per-bucket exclusive prefix over chunks -> hist becomes WITHIN-BUCKET offset
    if (tid < NB) {
        int run = 0;
        for (int c = 0; c < 256; ++c) {
            int t = hist[c][tid];
            hist[c][tid] = (unsigned short)run;
            run += t;
        }
        base[tid] = run;   // bucket count
    }
    __syncthreads();

    if (tid == 0) {
        int run = 0;
        if (which) {
            int* bstart = k_start + bh * (NB + 1);
            for (int b = 0; b < NB; ++b) {
                int t = base[b];
                base[b] = run;
                bstart[b] = run;
                run += t;
            }
            base[NB] = run;
            bstart[NB] = run;
        } else {
            for (int b = 0; b < NB; ++b) {
                int t = base[b];
                base[b] = run;                         // padded start
                run += (t + QPAD - 1) & ~(QPAD - 1);   // pad to multiple of 8
            }
        }
    }
    __syncthreads();

    // stable placement: slot = bucket_start + within-bucket offset
#pragma unroll
    for (int i = 0; i < 8; ++i) {
        int b   = myb[i];
        int ofs = base[b] + hist[tid][b];
        hist[tid][b]++;
        blist[ofs] = tid * 8 + i;
    }
}

// ---- Phase 3: wave per 8 same-bucket queries, no block barriers.
__global__ __launch_bounds__(256) void lsh_attn_g8(const float* __restrict__ Q,
                                                   const float* __restrict__ K,
                                                   const float* __restrict__ V,
                                                   const int* __restrict__ q_buckets,
                                                   const int* __restrict__ q_plist,
                                                   const int* __restrict__ k_start,
                                                   const int* __restrict__ k_list,
                                                   float* __restrict__ out) {
    __shared__ float wbuf[4][QPAD][64];   // [wave][query][key-lane]
    __shared__ int   kbuf[4][64];

    const int wv   = threadIdx.x >> 6;
    const int lane = threadIdx.x & 63;
    const int bh   = blockIdx.y;
    const int slot = (blockIdx.x * 4 + wv) * QPAD;     // < PADQ by construction

    const int* pl = q_plist + bh * PADQ + slot;
    int q[QPAD];
    bool vq[QPAD];
    q[0] = __builtin_amdgcn_readfirstlane(pl[0]);
    if (q[0] < 0) return;                               // all-sentinel group
#pragma unroll
    for (int j = 1; j < QPAD; ++j) {
        q[j] = __builtin_amdgcn_readfirstlane(pl[j]);
        vq[j] = q[j] >= 0;
        if (!vq[j]) q[j] = q[0];
    }

    const int bucket = __builtin_amdgcn_readfirstlane(q_buckets[bh * S_LEN + q[0]]);
    const int ks = k_start[bh * (NB + 1) + bucket];
    const int ke = k_start[bh * (NB + 1) + bucket + 1];
    const int nk = ke - ks;

    float* outb = out + (size_t)bh * S_LEN * D;
    if (nk == 0) {   // empty key bucket -> zero rows
        outb[(size_t)q[0] * D + lane] = 0.0f;
#pragma unroll
        for (int j = 1; j < QPAD; ++j)
            if (vq[j]) outb[(size_t)q[j] * D + lane] = 0.0f;
        return;
    }

    const int* kl   = k_list + bh * S_LEN + ks;
    const float* Kb = K + (size_t)bh * S_LEN * D;
    const float* Vb = V + (size_t)bh * S_LEN * D;
    const float* qr[QPAD];
#pragma unroll
    for (int j = 0; j < QPAD; ++j) qr[j] = Q + ((size_t)bh * S_LEN + q[j]) * D;

    float l[QPAD], acc[QPAD];
#pragma unroll
    for (int j = 0; j < QPAD; ++j) { l[j] = 0.f; acc[j] = 0.f; }

    for (int c = 0; c * 64 < nk; ++c) {
        const int cnk  = min(64, nk - c * 64);
        const int kidx = kl[c * 64 + min(lane, cnk - 1)];   // coalesced, clamped
        const float* krow = Kb + (size_t)kidx * D;

        // ---- scores: lane = key; K-row gather shared by 8 queries
        float s[QPAD];
#pragma unroll
        for (int j = 0; j < QPAD; ++j) s[j] = 0.f;
#pragma unroll
        for (int d4 = 0; d4 < 16; ++d4) {
            const float4 kv = *(const float4*)(krow + d4 * 4);   // gather
#pragma unroll
            for (int j = 0; j < QPAD; ++j) {
                const float4 qv = *(const float4*)(qr[j] + d4 * 4);  // s_load
                s[j] += qv.x * kv.x + qv.y * kv.y + qv.z * kv.z + qv.w * kv.w;
            }
        }

        // ---- no-max softmax accumulation: e = exp(s/8), l lane-distributed
        const bool kvalid = lane < cnk;
#pragma unroll
        for (int j = 0; j < QPAD; ++j) {
            const float e = kvalid ? __expf(s[j] * 0.125f) : 0.f;
            l[j] += e;
            wbuf[wv][j][lane] = e;
        }
        kbuf[wv][lane] = kidx;
        // same-wave LDS RAW: compiler inserts lgkmcnt wait

        // ---- PV: lane = dim; V rows shared by 8 queries
        const int ng = (cnk + 3) >> 2;
        for (int g = 0; g < ng; ++g) {
            const int4 kk = *(const int4*)&kbuf[wv][g * 4];
            const float vx = Vb[(size_t)kk.x * D + lane];
            const float vy = Vb[(size_t)kk.y * D + lane];
            const float vz = Vb[(size_t)kk.z * D + lane];
            const float vw = Vb[(size_t)kk.w * D + lane];
#pragma unroll
            for (int j = 0; j < QPAD; ++j) {
                const float4 e4 = *(const float4*)&wbuf[wv][j][g * 4];
                acc[j] += e4.x * vx + e4.y * vy + e4.z * vz + e4.w * vw;
            }
        }
    }

    // single end reduction of lane-distributed l
    float lr[QPAD];
#pragma unroll
    for (int j = 0; j < QPAD; ++j) lr[j] = l[j];
#pragma unroll
    for (int off = 32; off >= 1; off >>= 1) {
#pragma unroll
        for (int j = 0; j < QPAD; ++j) lr[j] += __shfl_xor(lr[j], off, 64);
    }

    const float inv6 = 1.0f / 6.0f;
    outb[(size_t)q[0] * D + lane] = acc[0] / (lr[0] + 1e-8f) * inv6;
#pragma unroll
    for (int j = 1; j < QPAD; ++j)
        if (vq[j]) outb[(size_t)q[j] * D + lane] = acc[j] / (lr[j] + 1e-8f) * inv6;
}

extern "C" void kernel_launch(void* const* d_in, const int* in_sizes, int n_in,
                              void* d_out, int out_size, void* d_ws, size_t ws_size,
                              hipStream_t stream) {
    const float* Q   = (const float*)d_in[0];
    const float* K   = (const float*)d_in[1];
    const float* V   = (const float*)d_in[2];
    const float* rot = (const float*)d_in[3];
    float* out = (float*)d_out;

    char* ws = (char*)d_ws;
    int* q_buckets = (int*)(ws);              // 128 KB
    int* k_buckets = (int*)(ws + 131072);     // 128 KB
    int* k_start   = (int*)(ws + 262144);     // 8 KB (16*65*4 used)
    int* k_list    = (int*)(ws + 270336);     // 128 KB
    int* q_plist   = (int*)(ws + 401408);     // 16*2496*4 = 156 KB

    lsh_buckets2<<<2 * BH * S_LEN / 4, 256, 0, stream>>>(Q, K, rot, q_buckets, k_buckets);
    lsh_build_lists3<<<32, 256, 0, stream>>>(q_buckets, k_buckets, q_plist, k_start, k_list);
    // PADQ/QPAD = 312 wave-slots per bh; 4 waves/block -> 78 blocks
    lsh_attn_g8<<<dim3(PADQ / QPAD / 4, BH), 256, 0, stream>>>(Q, K, V, q_buckets, q_plist,
                                                               k_start, k_list, out);
}

// Round 7
// 75.194 us; speedup vs baseline: 1.1735x; 1.1735x over previous
//
#include <hip/hip_runtime.h>
#include <math.h>

// LSH attention: B=2, H=8, S=2048, D=64, 6 bits -> 64 buckets, exact-match.
// Phase 1: bucket codes for Q and K (fused, sign of X.rot)
// Phase 2: stable counting sort; Q list 4-PADDED per bucket, entries packed
//          qidx | (bucket<<16), sentinel -1. K side: bucket_start + list.
// Phase 3: wave per 4 same-bucket queries, barrier-free, 32-key chunks with
//          half-wave D-split scores (lane = 32h+k: partial dot over dim-half h
//          for all 4 queries, one shfl_xor(32) combine). Q rows in per-wave
//          LDS. No-max softmax (exp direct, linear accumulation). lane=dim PV.

constexpr int S_LEN = 2048;
constexpr int D = 64;
constexpr int NHASH = 6;
constexpr int BH = 16;     // B*H
constexpr int NB = 64;     // 2^NHASH
constexpr int QPAD = 4;    // queries per wave
constexpr int PADQ = S_LEN + (QPAD - 1) * NB;   // 2240
constexpr int KCH = 32;    // key-chunk width (matches ~32-key buckets)

// ---- Phase 1: bucket codes for Q and K in one dispatch. One wave per vector.
__global__ __launch_bounds__(256) void lsh_buckets2(const float* __restrict__ Q,
                                                    const float* __restrict__ K,
                                                    const float* __restrict__ rot,
                                                    int* __restrict__ qb,
                                                    int* __restrict__ kb) {
    const int gw   = (blockIdx.x * 256 + threadIdx.x) >> 6;
    const int lane = threadIdx.x & 63;
    const bool isK = gw >= BH * S_LEN;
    const int wid  = isK ? gw - BH * S_LEN : gw;
    const float* X = isK ? K : Q;
    int* dst       = isK ? kb : qb;
    const int h    = (wid >> 11) & 7;

    const float x  = X[(size_t)wid * D + lane];
    const float* r = rot + (size_t)h * NHASH * D + lane;
    float p0 = x * r[0 * D], p1 = x * r[1 * D], p2 = x * r[2 * D];
    float p3 = x * r[3 * D], p4 = x * r[4 * D], p5 = x * r[5 * D];
#pragma unroll
    for (int off = 32; off >= 1; off >>= 1) {
        p0 += __shfl_xor(p0, off, 64);
        p1 += __shfl_xor(p1, off, 64);
        p2 += __shfl_xor(p2, off, 64);
        p3 += __shfl_xor(p3, off, 64);
        p4 += __shfl_xor(p4, off, 64);
        p5 += __shfl_xor(p5, off, 64);
    }
    int bucket = (p0 > 0.f ? 1 : 0) | (p1 > 0.f ? 2 : 0) | (p2 > 0.f ? 4 : 0) |
                 (p3 > 0.f ? 8 : 0) | (p4 > 0.f ? 16 : 0) | (p5 > 0.f ? 32 : 0);
    if (lane == 0) dst[wid] = bucket;
}

// ---- Phase 2: stable counting sort, one block per (which, bh). which: 0=Q 1=K
// Q side: 4-padded list, entry = qidx | (bucket<<16), sentinel -1.
// K side: unpadded list + bucket_start table.
__global__ __launch_bounds__(256) void lsh_build_lists4(const int* __restrict__ qbuckets,
                                                        const int* __restrict__ kbuckets,
                                                        int* __restrict__ q_plist,
                                                        int* __restrict__ k_start,
                                                        int* __restrict__ k_list) {
    __shared__ unsigned short hist[256][NB + 1];
    __shared__ int base[NB + 1];
    const int which = blockIdx.x >> 4;   // 0 = Q (padded), 1 = K
    const int bh    = blockIdx.x & 15;
    const int tid   = threadIdx.x;
    const int* src  = (which ? kbuckets : qbuckets) + bh * S_LEN;
    int* blist      = which ? (k_list + bh * S_LEN) : (q_plist + bh * PADQ);

    if (!which) {  // prefill padded list with sentinels
        for (int t = tid; t < PADQ; t += 256) blist[t] = -1;
    }

    for (int b = 0; b <= NB; ++b) hist[tid][b] = 0;

    int myb[8];
#pragma unroll
    for (int i = 0; i < 8; ++i) {
        int b = src[tid * 8 + i];
        myb[i] = b;
        hist[tid][b]++;
    }
    __syncthreads();

    // per-bucket exclusive prefix over chunks -> hist becomes WITHIN-BUCKET offset
    if (tid < NB) {
        int run = 0;
        for (int c = 0; c < 256; ++c) {
            int t = hist[c][tid];
            hist[c][tid] = (unsigned short)run;
            run += t;
        }
        base[tid] = run;   // bucket count
    }
    __syncthreads();

    if (tid == 0) {
        int run = 0;
        if (which) {
            int* bstart = k_start + bh * (NB + 1);
            for (int b = 0; b < NB; ++b) {
                int t = base[b];
                base[b] = run;
                bstart[b] = run;
                run += t;
            }
            base[NB] = run;
            bstart[NB] = run;
        } else {
            for (int b = 0; b < NB; ++b) {
                int t = base[b];
                base[b] = run;                         // padded start
                run += (t + QPAD - 1) & ~(QPAD - 1);   // pad to multiple of 4
            }
        }
    }
    __syncthreads();

    // stable placement: slot = bucket_start + within-bucket offset
#pragma unroll
    for (int i = 0; i < 8; ++i) {
        int b   = myb[i];
        int ofs = base[b] + hist[tid][b];
        hist[tid][b]++;
        int val = tid * 8 + i;
        if (!which) val |= (b << 16);
        blist[ofs] = val;
    }
}

// ---- Phase 3: wave per 4 same-bucket queries, 32-key chunks, half-wave D-split.
__global__ __launch_bounds__(256) void lsh_attn_h32(const float* __restrict__ Q,
                                                    const float* __restrict__ K,
                                                    const float* __restrict__ V,
                                                    const int* __restrict__ q_plist,
                                                    const int* __restrict__ k_start,
                                                    const int* __restrict__ k_list,
                                                    float* __restrict__ out) {
    __shared__ float qlds[4][QPAD][64];   // staged Q rows, per wave
    __shared__ float wbuf[4][QPAD][KCH];  // exp weights, per wave
    __shared__ int   kbuf[4][KCH];        // key indices, per wave

    const int wv   = threadIdx.x >> 6;
    const int lane = threadIdx.x & 63;
    const int h    = lane >> 5;           // dim-half / query-pair owner
    const int kk   = lane & 31;           // key slot within chunk
    const int bh   = blockIdx.y;
    const int slot = (blockIdx.x * 4 + wv) * QPAD;

    const int* pl = q_plist + bh * PADQ + slot;
    const int e0 = __builtin_amdgcn_readfirstlane(pl[0]);
    if (e0 < 0) return;                   // all-sentinel group
    const int bucket = e0 >> 16;

    int q[QPAD];
    bool vq[QPAD];
    q[0] = e0 & 0xFFFF;
#pragma unroll
    for (int j = 1; j < QPAD; ++j) {
        const int ej = __builtin_amdgcn_readfirstlane(pl[j]);
        vq[j] = ej >= 0;
        q[j] = vq[j] ? (ej & 0xFFFF) : q[0];
    }

    const int ks = k_start[bh * (NB + 1) + bucket];
    const int ke = k_start[bh * (NB + 1) + bucket + 1];
    const int nk = ke - ks;

    float* outb = out + (size_t)bh * S_LEN * D;
    if (nk == 0) {   // empty key bucket -> zero rows
        outb[(size_t)q[0] * D + lane] = 0.0f;
#pragma unroll
        for (int j = 1; j < QPAD; ++j)
            if (vq[j]) outb[(size_t)q[j] * D + lane] = 0.0f;
        return;
    }

    const int* kl   = k_list + bh * S_LEN + ks;
    const float* Kb = K + (size_t)bh * S_LEN * D;
    const float* Vb = V + (size_t)bh * S_LEN * D;

    // stage the 4 Q rows into per-wave LDS (coalesced; same-wave RAW is ordered)
#pragma unroll
    for (int j = 0; j < QPAD; ++j)
        qlds[wv][j][lane] = Q[((size_t)bh * S_LEN + q[j]) * D + lane];

    float l0 = 0.f, l1 = 0.f;             // this lane's 2 owned queries (2h, 2h+1)
    float acc[QPAD] = {0.f, 0.f, 0.f, 0.f};

    for (int c = 0; c * KCH < nk; ++c) {
        const int cnk  = min(KCH, nk - c * KCH);
        const int kidx = kl[c * KCH + min(kk, cnk - 1)];   // coalesced, clamped
        const float* krow = Kb + (size_t)kidx * D + h * 32; // this lane's dim-half

        // ---- partial scores over dim-half h for ALL 4 queries at key kk
        float s0 = 0.f, s1 = 0.f, s2 = 0.f, s3 = 0.f;
#pragma unroll
        for (int i = 0; i < 8; ++i) {
            const float4 kv = *(const float4*)(krow + i * 4);            // gather (half-row)
            const float4 qa = *(const float4*)&qlds[wv][0][h * 32 + i * 4]; // broadcast
            const float4 qb = *(const float4*)&qlds[wv][1][h * 32 + i * 4];
            const float4 qc = *(const float4*)&qlds[wv][2][h * 32 + i * 4];
            const float4 qd = *(const float4*)&qlds[wv][3][h * 32 + i * 4];
            s0 += qa.x * kv.x + qa.y * kv.y + qa.z * kv.z + qa.w * kv.w;
            s1 += qb.x * kv.x + qb.y * kv.y + qb.z * kv.z + qb.w * kv.w;
            s2 += qc.x * kv.x + qc.y * kv.y + qc.z * kv.z + qc.w * kv.w;
            s3 += qd.x * kv.x + qd.y * kv.y + qd.z * kv.z + qd.w * kv.w;
        }
        // combine the two dim-halves (same key kk lives in lanes kk and kk+32)
        s0 += __shfl_xor(s0, 32, 64);
        s1 += __shfl_xor(s1, 32, 64);
        s2 += __shfl_xor(s2, 32, 64);
        s3 += __shfl_xor(s3, 32, 64);

        // ---- each half owns 2 queries: exp + linear l accumulation
        const bool kvalid = kk < cnk;
        const float sa = h ? s2 : s0;
        const float sb = h ? s3 : s1;
        const float ea = kvalid ? __expf(sa * 0.125f) : 0.f;
        const float eb = kvalid ? __expf(sb * 0.125f) : 0.f;
        l0 += ea;
        l1 += eb;
        wbuf[wv][2 * h + 0][kk] = ea;
        wbuf[wv][2 * h + 1][kk] = eb;
        if (h == 0) kbuf[wv][kk] = kidx;
        // same-wave LDS RAW: compiler inserts lgkmcnt wait

        // ---- PV: lane = dim; V rows shared by 4 queries
        const int ng = (cnk + 3) >> 2;
        for (int g = 0; g < ng; ++g) {
            const int4 kx = *(const int4*)&kbuf[wv][g * 4];
            const float vx = Vb[(size_t)kx.x * D + lane];
            const float vy = Vb[(size_t)kx.y * D + lane];
            const float vz = Vb[(size_t)kx.z * D + lane];
            const float vw = Vb[(size_t)kx.w * D + lane];
            const float4 eA = *(const float4*)&wbuf[wv][0][g * 4];
            const float4 eB = *(const float4*)&wbuf[wv][1][g * 4];
            const float4 eC = *(const float4*)&wbuf[wv][2][g * 4];
            const float4 eD = *(const float4*)&wbuf[wv][3][g * 4];
            acc[0] += eA.x * vx + eA.y * vy + eA.z * vz + eA.w * vw;
            acc[1] += eB.x * vx + eB.y * vy + eB.z * vz + eB.w * vw;
            acc[2] += eC.x * vx + eC.y * vy + eC.z * vz + eC.w * vw;
            acc[3] += eD.x * vx + eD.y * vy + eD.z * vz + eD.w * vw;
        }
    }

    // reduce l within each 32-lane half (owned queries), then swap halves
#pragma unroll
    for (int off = 16; off >= 1; off >>= 1) {
        l0 += __shfl_xor(l0, off, 64);
        l1 += __shfl_xor(l1, off, 64);
    }
    const float o0 = __shfl_xor(l0, 32, 64);
    const float o1 = __shfl_xor(l1, 32, 64);
    const float lq0 = h ? o0 : l0;
    const float lq1 = h ? o1 : l1;
    const float lq2 = h ? l0 : o0;
    const float lq3 = h ? l1 : o1;

    const float inv6 = 1.0f / 6.0f;
    outb[(size_t)q[0] * D + lane] = acc[0] / (lq0 + 1e-8f) * inv6;
    if (vq[1]) outb[(size_t)q[1] * D + lane] = acc[1] / (lq1 + 1e-8f) * inv6;
    if (vq[2]) outb[(size_t)q[2] * D + lane] = acc[2] / (lq2 + 1e-8f) * inv6;
    if (vq[3]) outb[(size_t)q[3] * D + lane] = acc[3] / (lq3 + 1e-8f) * inv6;
}

extern "C" void kernel_launch(void* const* d_in, const int* in_sizes, int n_in,
                              void* d_out, int out_size, void* d_ws, size_t ws_size,
                              hipStream_t stream) {
    const float* Q   = (const float*)d_in[0];
    const float* K   = (const float*)d_in[1];
    const float* V   = (const float*)d_in[2];
    const float* rot = (const float*)d_in[3];
    float* out = (float*)d_out;

    char* ws = (char*)d_ws;
    int* q_buckets = (int*)(ws);              // 128 KB
    int* k_buckets = (int*)(ws + 131072);     // 128 KB
    int* k_start   = (int*)(ws + 262144);     // 8 KB (16*65*4 used)
    int* k_list    = (int*)(ws + 270336);     // 128 KB
    int* q_plist   = (int*)(ws + 401408);     // 16*2240*4 = 140 KB

    lsh_buckets2<<<2 * BH * S_LEN / 4, 256, 0, stream>>>(Q, K, rot, q_buckets, k_buckets);
    lsh_build_lists4<<<32, 256, 0, stream>>>(q_buckets, k_buckets, q_plist, k_start, k_list);
    // 560 wave-slots per bh, 4 waves/block -> 140 blocks x 16 bh
    lsh_attn_h32<<<dim3(PADQ / QPAD / 4, BH), 256, 0, stream>>>(Q, K, V, q_plist,
                                                                k_start, k_list, out);
}